// Round 1
// baseline (771.362 us; speedup 1.0000x reference)
//
#include <hip/hip_runtime.h>
#include <hip/hip_bf16.h>

// GCN layer: out = D^-1/2 (A + I) D^-1/2 (x W^T + b)
// Pipeline per launch (graph-capture safe, same work every call):
//   0. memsetAsync cnt=0
//   1. hist:  cnt[d] += 1 per edge (in-degree, self-loop added later as +1)
//   2. scan:  off = exclusive prefix of cnt (single 1024-thread block)
//   3. rinv:  rinv[i] = rsqrt(cnt[i] + 1)
//   4. fill:  CSR-by-dst; pos = atomicAdd(&off[d],1); after this pass
//             off[i] == start of segment i+1 (the classic shift trick)
//   5. gemm:  h = x W^T + b   (fp32 vector ALU, LDS tiled, 4x4 reg blocking)
//   6. spmm:  out[i] = rinv[i] * (sum_e rinv[src_e] h[src_e] + rinv[i] h[i])

#define N_NODES 100000
#define N_EDGES 1600000
#define CH 128

// ---------------- histogram ----------------
__global__ __launch_bounds__(256) void k_hist(const int* __restrict__ dst,
                                              int* __restrict__ cnt) {
    int e = blockIdx.x * 256 + threadIdx.x;   // grid exactly covers E
    atomicAdd(&cnt[dst[e]], 1);
}

// ---------------- exclusive scan (single block) ----------------
__global__ __launch_bounds__(1024) void k_scan(const int* __restrict__ cnt,
                                               int* __restrict__ off) {
    __shared__ int sums[1024];
    const int t = threadIdx.x;
    const int CHUNK = 98;                      // 1024*98 = 100352 >= N
    int begin = t * CHUNK;
    int end   = begin + CHUNK; if (end > N_NODES) end = N_NODES;
    int s = 0;
    for (int i = begin; i < end; ++i) s += cnt[i];
    sums[t] = s;
    __syncthreads();
    int val = s;
    for (int d = 1; d < 1024; d <<= 1) {
        int other = (t >= d) ? sums[t - d] : 0;
        __syncthreads();
        val += other;
        sums[t] = val;
        __syncthreads();
    }
    int run = (t == 0) ? 0 : sums[t - 1];      // exclusive base
    for (int i = begin; i < end; ++i) {
        off[i] = run;
        run += cnt[i];
    }
}

// ---------------- rinv = 1/sqrt(deg) ----------------
__global__ __launch_bounds__(256) void k_rinv(const int* __restrict__ cnt,
                                              float* __restrict__ rinv) {
    int i = blockIdx.x * 256 + threadIdx.x;
    if (i < N_NODES) rinv[i] = rsqrtf((float)(cnt[i] + 1));
}

// ---------------- CSR fill ----------------
__global__ __launch_bounds__(256) void k_fill(const int* __restrict__ src,
                                              const int* __restrict__ dst,
                                              int* __restrict__ off,
                                              int* __restrict__ csr_src) {
    int e = blockIdx.x * 256 + threadIdx.x;   // grid exactly covers E
    int d = dst[e];
    int pos = atomicAdd(&off[d], 1);
    csr_src[pos] = src[e];
}

// ---------------- GEMM: h = x * W^T + b ----------------
// 32 rows x 128 cols per block, 256 threads, each thread 4x4 micro-tile.
// Rows for thread: ty + 8*i (conflict-free b128 LDS reads with stride 36).
__global__ __launch_bounds__(256) void k_gemm(const float* __restrict__ x,
                                              const float* __restrict__ W,
                                              const float* __restrict__ b,
                                              float* __restrict__ h) {
    __shared__ __align__(16) float xs[32][36];    // [row][kk]  stride 36 floats
    __shared__ __align__(16) float ws[32][132];   // [kk][o]    stride 132 floats
    const int t  = threadIdx.x;
    const int tx = t & 31;          // output cols o = 4*tx + c
    const int ty = t >> 5;          // rows r = ty + 8*i
    const int row0 = blockIdx.x * 32;

    float acc[4][4] = {};

    for (int k0 = 0; k0 < CH; k0 += 32) {
        // stage x tile: coalesced global (32 consecutive kk per row)
        {
            int r  = t >> 5;
            int kk = t & 31;
            for (int p = 0; p < 4; ++p) {
                int rr = r + p * 8;
                xs[rr][kk] = x[(size_t)(row0 + rr) * CH + k0 + kk];
            }
            // stage W transposed: ws[kk][o] = W[o][k0+kk]
            int o = t >> 5;
            for (int p = 0; p < 16; ++p) {
                int oo = o + p * 8;
                ws[kk][oo] = W[(size_t)oo * CH + k0 + kk];
            }
        }
        __syncthreads();

        for (int k4 = 0; k4 < 32; k4 += 4) {
            float4 xv[4], wv[4];
            for (int i = 0; i < 4; ++i)
                xv[i] = *(const float4*)&xs[ty + 8 * i][k4];
            for (int j = 0; j < 4; ++j)
                wv[j] = *(const float4*)&ws[k4 + j][4 * tx];
            for (int i = 0; i < 4; ++i) {
                acc[i][0] += xv[i].x * wv[0].x;
                acc[i][1] += xv[i].x * wv[0].y;
                acc[i][2] += xv[i].x * wv[0].z;
                acc[i][3] += xv[i].x * wv[0].w;
                acc[i][0] += xv[i].y * wv[1].x;
                acc[i][1] += xv[i].y * wv[1].y;
                acc[i][2] += xv[i].y * wv[1].z;
                acc[i][3] += xv[i].y * wv[1].w;
                acc[i][0] += xv[i].z * wv[2].x;
                acc[i][1] += xv[i].z * wv[2].y;
                acc[i][2] += xv[i].z * wv[2].z;
                acc[i][3] += xv[i].z * wv[2].w;
                acc[i][0] += xv[i].w * wv[3].x;
                acc[i][1] += xv[i].w * wv[3].y;
                acc[i][2] += xv[i].w * wv[3].z;
                acc[i][3] += xv[i].w * wv[3].w;
            }
        }
        __syncthreads();
    }

    float4 bv = *(const float4*)&b[4 * tx];
    for (int i = 0; i < 4; ++i) {
        float4 o4;
        o4.x = acc[i][0] + bv.x;
        o4.y = acc[i][1] + bv.y;
        o4.z = acc[i][2] + bv.z;
        o4.w = acc[i][3] + bv.w;
        *(float4*)&h[(size_t)(row0 + ty + 8 * i) * CH + 4 * tx] = o4;
    }
}

// ---------------- SpMM gather ----------------
// 2 nodes per 256-thread block; 128 threads (one channel each) per node.
// After k_fill, segment i spans [ i==0 ? 0 : off[i-1], off[i] ).
__global__ __launch_bounds__(256) void k_spmm(const int* __restrict__ csr_src,
                                              const int* __restrict__ off,
                                              const float* __restrict__ rinv,
                                              const float* __restrict__ h,
                                              float* __restrict__ out) {
    int node = blockIdx.x * 2 + (threadIdx.x >> 7);
    int c    = threadIdx.x & 127;
    if (node >= N_NODES) return;
    int start = (node == 0) ? 0 : off[node - 1];
    int end   = off[node];
    float acc = 0.f;
    for (int e = start; e < end; ++e) {
        int s = csr_src[e];
        acc += rinv[s] * h[(size_t)s * CH + c];
    }
    float ri = rinv[node];
    out[(size_t)node * CH + c] = ri * (acc + ri * h[(size_t)node * CH + c]);
}

extern "C" void kernel_launch(void* const* d_in, const int* in_sizes, int n_in,
                              void* d_out, int out_size, void* d_ws, size_t ws_size,
                              hipStream_t stream) {
    const float* x  = (const float*)d_in[0];
    const int*   ei = (const int*)d_in[1];     // [2][E] int32 per harness contract
    const float* W  = (const float*)d_in[2];
    const float* b  = (const float*)d_in[3];
    float* out = (float*)d_out;

    const int* src = ei;
    const int* dst = ei + N_EDGES;

    // workspace layout (4-byte elements)
    int*   cnt     = (int*)d_ws;                         // N
    int*   off     = cnt + N_NODES;                      // N
    float* rinv    = (float*)(off + N_NODES);            // N
    int*   csr_src = (int*)(rinv + N_NODES);             // E
    float* h       = (float*)(csr_src + N_EDGES);        // N*CH  (16B-aligned: 7.6e6 B offset)

    hipMemsetAsync(cnt, 0, N_NODES * sizeof(int), stream);

    k_hist<<<N_EDGES / 256, 256, 0, stream>>>(dst, cnt);
    k_scan<<<1, 1024, 0, stream>>>(cnt, off);
    k_rinv<<<(N_NODES + 255) / 256, 256, 0, stream>>>(cnt, rinv);
    k_fill<<<N_EDGES / 256, 256, 0, stream>>>(src, dst, off, csr_src);
    k_gemm<<<N_NODES / 32, 256, 0, stream>>>(x, W, b, h);
    k_spmm<<<N_NODES / 2, 256, 0, stream>>>(csr_src, off, rinv, h, out);
}

// Round 2
// 393.880 us; speedup vs baseline: 1.9584x; 1.9584x over previous
//
#include <hip/hip_runtime.h>
#include <hip/hip_bf16.h>

// GCN layer: out = D^-1/2 (A + I) D^-1/2 (x W^T + b)
// R2 pipeline:
//   0. memset cnt
//   1. hist:   cnt[d]++ per edge
//   2. scan1/2/3: multi-block exclusive scan cnt->off, + rinv=rsqrt(cnt+1)
//   3. fill:   CSR-by-dst (off becomes segment-end after this pass)
//   4. gemm:   hs = bf16( rinv[r] * (x W^T + b) )   <- rinv folded in, bf16 halves gather
//   5. spmm:   out[i] = rinv[i] * ( sum_e hs[src_e] + hs[i] )   (fp32 accumulate)

#define N_NODES 100000
#define N_EDGES 1600000
#define CH 128
#define SC 8            // scan elems per thread; 64 blocks * 256 thr * 8 = 131072 >= N

__device__ inline unsigned short f2bf(float f) {          // RNE float->bf16
    unsigned u = __float_as_uint(f);
    u += 0x7fffu + ((u >> 16) & 1u);
    return (unsigned short)(u >> 16);
}
__device__ inline float bflo(unsigned u) { return __uint_as_float(u << 16); }
__device__ inline float bfhi(unsigned u) { return __uint_as_float(u & 0xffff0000u); }

// ---------------- histogram ----------------
__global__ __launch_bounds__(256) void k_hist(const int* __restrict__ dst,
                                              int* __restrict__ cnt) {
    int e = blockIdx.x * 256 + threadIdx.x;   // grid exactly covers E
    atomicAdd(&cnt[dst[e]], 1);
}

// ---------------- scan phase 1: per-block sums ----------------
__global__ __launch_bounds__(256) void k_scan1(const int* __restrict__ cnt,
                                               int* __restrict__ part) {
    __shared__ int lds[256];
    const int t = threadIdx.x, b = blockIdx.x;
    const int base = (b * 256 + t) * SC;
    int s = 0;
#pragma unroll
    for (int j = 0; j < SC; ++j) {
        int i = base + j;
        if (i < N_NODES) s += cnt[i];
    }
    lds[t] = s;
    __syncthreads();
    for (int d = 1; d < 256; d <<= 1) {
        int v = (t >= d) ? lds[t - d] : 0;
        __syncthreads();
        lds[t] += v;
        __syncthreads();
    }
    if (t == 255) part[b] = lds[255];
}

// ---------------- scan phase 2: scan 64 block sums (1 wave) ----------------
__global__ __launch_bounds__(64) void k_scan2(int* __restrict__ part) {
    int t = threadIdx.x;
    int orig = part[t];
    int v = orig;
    for (int d = 1; d < 64; d <<= 1) {
        int w = __shfl_up(v, d);
        if (t >= d) v += w;
    }
    part[t] = v - orig;                         // exclusive base per block
}

// ---------------- scan phase 3: write off (exclusive) + rinv ----------------
__global__ __launch_bounds__(256) void k_scan3(const int* __restrict__ cnt,
                                               const int* __restrict__ part,
                                               int* __restrict__ off,
                                               float* __restrict__ rinv) {
    __shared__ int lds[256];
    const int t = threadIdx.x, b = blockIdx.x;
    const int base = (b * 256 + t) * SC;
    int c[SC];
    int s = 0;
#pragma unroll
    for (int j = 0; j < SC; ++j) {
        int i = base + j;
        c[j] = (i < N_NODES) ? cnt[i] : 0;
        s += c[j];
    }
    lds[t] = s;
    __syncthreads();
    for (int d = 1; d < 256; d <<= 1) {
        int v = (t >= d) ? lds[t - d] : 0;
        __syncthreads();
        lds[t] += v;
        __syncthreads();
    }
    int run = part[b] + lds[t] - s;             // block base + thread-exclusive
#pragma unroll
    for (int j = 0; j < SC; ++j) {
        int i = base + j;
        if (i < N_NODES) {
            off[i] = run;
            rinv[i] = rsqrtf((float)(c[j] + 1));
            run += c[j];
        }
    }
}

// ---------------- CSR fill ----------------
__global__ __launch_bounds__(256) void k_fill(const int* __restrict__ src,
                                              const int* __restrict__ dst,
                                              int* __restrict__ off,
                                              int* __restrict__ csr_src) {
    int e = blockIdx.x * 256 + threadIdx.x;   // grid exactly covers E
    int d = dst[e];
    int pos = atomicAdd(&off[d], 1);
    csr_src[pos] = src[e];
}

// ---------------- GEMM: hs = bf16( rinv * (x W^T + b) ) ----------------
// 32 rows x 128 cols per block, 256 threads, 4x4 micro-tile per thread.
__global__ __launch_bounds__(256) void k_gemm(const float* __restrict__ x,
                                              const float* __restrict__ W,
                                              const float* __restrict__ b,
                                              const float* __restrict__ rinv,
                                              unsigned short* __restrict__ hs) {
    __shared__ __align__(16) float xs[32][36];    // [row][kk]
    __shared__ __align__(16) float ws[32][132];   // [kk][o]
    const int t  = threadIdx.x;
    const int tx = t & 31;          // output cols o = 4*tx + c
    const int ty = t >> 5;          // rows r = ty + 8*i
    const int row0 = blockIdx.x * 32;

    float acc[4][4] = {};

    for (int k0 = 0; k0 < CH; k0 += 32) {
        {
            int r  = t >> 5;
            int kk = t & 31;
            for (int p = 0; p < 4; ++p) {
                int rr = r + p * 8;
                xs[rr][kk] = x[(size_t)(row0 + rr) * CH + k0 + kk];
            }
            int o = t >> 5;
            for (int p = 0; p < 16; ++p) {
                int oo = o + p * 8;
                ws[kk][oo] = W[(size_t)oo * CH + k0 + kk];
            }
        }
        __syncthreads();

        for (int k4 = 0; k4 < 32; k4 += 4) {
            float4 xv[4], wv[4];
            for (int i = 0; i < 4; ++i)
                xv[i] = *(const float4*)&xs[ty + 8 * i][k4];
            for (int j = 0; j < 4; ++j)
                wv[j] = *(const float4*)&ws[k4 + j][4 * tx];
            for (int i = 0; i < 4; ++i) {
                acc[i][0] += xv[i].x * wv[0].x; acc[i][1] += xv[i].x * wv[0].y;
                acc[i][2] += xv[i].x * wv[0].z; acc[i][3] += xv[i].x * wv[0].w;
                acc[i][0] += xv[i].y * wv[1].x; acc[i][1] += xv[i].y * wv[1].y;
                acc[i][2] += xv[i].y * wv[1].z; acc[i][3] += xv[i].y * wv[1].w;
                acc[i][0] += xv[i].z * wv[2].x; acc[i][1] += xv[i].z * wv[2].y;
                acc[i][2] += xv[i].z * wv[2].z; acc[i][3] += xv[i].z * wv[2].w;
                acc[i][0] += xv[i].w * wv[3].x; acc[i][1] += xv[i].w * wv[3].y;
                acc[i][2] += xv[i].w * wv[3].z; acc[i][3] += xv[i].w * wv[3].w;
            }
        }
        __syncthreads();
    }

    float4 bv = *(const float4*)&b[4 * tx];
    for (int i = 0; i < 4; ++i) {
        int r = row0 + ty + 8 * i;
        float ri = rinv[r];
        ushort4 o4;
        o4.x = f2bf(ri * (acc[i][0] + bv.x));
        o4.y = f2bf(ri * (acc[i][1] + bv.y));
        o4.z = f2bf(ri * (acc[i][2] + bv.z));
        o4.w = f2bf(ri * (acc[i][3] + bv.w));
        *(ushort4*)&hs[(size_t)r * CH + 4 * tx] = o4;
    }
}

// ---------------- SpMM gather ----------------
// 16 nodes per 256-thread block; 16 lanes/node, 8 bf16 channels per lane (uint4).
// 4-edge unroll for memory-level parallelism. fp32 accumulate.
#define ACC8(u)                                                            \
    do {                                                                   \
        acc[0] += bflo((u).x); acc[1] += bfhi((u).x);                      \
        acc[2] += bflo((u).y); acc[3] += bfhi((u).y);                      \
        acc[4] += bflo((u).z); acc[5] += bfhi((u).z);                      \
        acc[6] += bflo((u).w); acc[7] += bfhi((u).w);                      \
    } while (0)

__global__ __launch_bounds__(256) void k_spmm(const int* __restrict__ csr_src,
                                              const int* __restrict__ off,
                                              const float* __restrict__ rinv,
                                              const unsigned short* __restrict__ hs,
                                              float* __restrict__ out) {
    const int node = blockIdx.x * 16 + (threadIdx.x >> 4);  // grid exact: 6250*16
    const int lane = threadIdx.x & 15;
    const int c0   = lane * 8;
    const uint4* hp = (const uint4*)hs;      // row s at hp[s*16 + lane]

    const int start = (node == 0) ? 0 : off[node - 1];
    const int end   = off[node];

    float acc[8] = {};
    {   // self term
        uint4 u = hp[(size_t)node * 16 + lane];
        ACC8(u);
    }
    int e = start;
    for (; e + 4 <= end; e += 4) {
        int s0 = csr_src[e + 0];
        int s1 = csr_src[e + 1];
        int s2 = csr_src[e + 2];
        int s3 = csr_src[e + 3];
        uint4 u0 = hp[(size_t)s0 * 16 + lane];
        uint4 u1 = hp[(size_t)s1 * 16 + lane];
        uint4 u2 = hp[(size_t)s2 * 16 + lane];
        uint4 u3 = hp[(size_t)s3 * 16 + lane];
        ACC8(u0); ACC8(u1); ACC8(u2); ACC8(u3);
    }
    for (; e < end; ++e) {
        int s = csr_src[e];
        uint4 u = hp[(size_t)s * 16 + lane];
        ACC8(u);
    }

    float ri = rinv[node];
    float4 o0, o1;
    o0.x = ri * acc[0]; o0.y = ri * acc[1]; o0.z = ri * acc[2]; o0.w = ri * acc[3];
    o1.x = ri * acc[4]; o1.y = ri * acc[5]; o1.z = ri * acc[6]; o1.w = ri * acc[7];
    *(float4*)&out[(size_t)node * CH + c0]     = o0;
    *(float4*)&out[(size_t)node * CH + c0 + 4] = o1;
}

extern "C" void kernel_launch(void* const* d_in, const int* in_sizes, int n_in,
                              void* d_out, int out_size, void* d_ws, size_t ws_size,
                              hipStream_t stream) {
    const float* x  = (const float*)d_in[0];
    const int*   ei = (const int*)d_in[1];
    const float* W  = (const float*)d_in[2];
    const float* b  = (const float*)d_in[3];
    float* out = (float*)d_out;

    const int* src = ei;
    const int* dst = ei + N_EDGES;

    // workspace layout (4-byte units unless noted)
    int*   cnt     = (int*)d_ws;                          // N
    int*   off     = cnt + N_NODES;                       // N
    float* rinv    = (float*)(off + N_NODES);             // N
    int*   part    = (int*)(rinv + N_NODES);              // 256 (64 used)
    int*   csr_src = part + 256;                          // E
    unsigned short* hs = (unsigned short*)(csr_src + N_EDGES);  // N*CH bf16, 16B-aligned

    hipMemsetAsync(cnt, 0, N_NODES * sizeof(int), stream);

    k_hist<<<N_EDGES / 256, 256, 0, stream>>>(dst, cnt);
    k_scan1<<<64, 256, 0, stream>>>(cnt, part);
    k_scan2<<<1, 64, 0, stream>>>(part);
    k_scan3<<<64, 256, 0, stream>>>(cnt, part, off, rinv);
    k_fill<<<N_EDGES / 256, 256, 0, stream>>>(src, dst, off, csr_src);
    k_gemm<<<N_NODES / 32, 256, 0, stream>>>(x, W, b, rinv, hs);
    k_spmm<<<N_NODES / 16, 256, 0, stream>>>(csr_src, off, rinv, hs, out);
}